// Round 1
// 3400.541 us; speedup vs baseline: 1.0974x; 1.0974x over previous
//
#include <hip/hip_runtime.h>
#include <cstdint>
#include <cstddef>

#define HDIM 128
#define TM 128
#define TK 32
#define SCHUNK 1024

__device__ __forceinline__ float sigmoidf_(float x) {
  return 1.0f / (1.0f + __expf(-x));
}

// ---------------- f32 GEMM: C[M,128] (+)= A[M,K] @ W[K,128] (+bias)(+relu)
// 128x128 tile, 256 threads, 8x8 acc per thread (2x2 sub-block layout),
// A staged transposed in LDS -> inner loop is 4x ds_read_b128 per 64 FMA.
__global__ __launch_bounds__(256) void gemm128(
    const float* __restrict__ A, const float* __restrict__ W,
    const float* __restrict__ bias, float* __restrict__ C,
    int M, int K, int accumulate, int post)
{
  __shared__ float At[TK][TM + 4];    // transposed A tile [k][m], 132 stride (16B aligned)
  __shared__ float Ws[TK][HDIM + 4];  // W tile [k][n]
  const int m0 = blockIdx.x * TM;
  const int tid = threadIdx.x;
  const int tx = tid & 15;   // cols tx*4..+3 and 64+tx*4..+3
  const int ty = tid >> 4;   // rows ty*4..+3 and 64+ty*4..+3

  float acc[8][8];
#pragma unroll
  for (int i = 0; i < 8; ++i)
#pragma unroll
    for (int j = 0; j < 8; ++j) acc[i][j] = 0.f;

  const int arow = tid >> 3;         // A stage: row within 32-row group
  const int ac4  = (tid & 7) * 4;    // A stage: k-col base
  const int wrow = tid >> 5;         // W stage: k-row within 8-row group
  const int wc4  = (tid & 31) * 4;   // W stage: col base

  for (int k0 = 0; k0 < K; k0 += TK) {
    // stage A (transposed): 128 rows x 32 k, 4 float4 per thread
#pragma unroll
    for (int q = 0; q < 4; ++q) {
      int row = q * 32 + arow;
      int gr = m0 + row;
      float4 v = make_float4(0.f, 0.f, 0.f, 0.f);
      if (gr < M) v = *(const float4*)(A + (long long)gr * K + k0 + ac4);
      At[ac4 + 0][row] = v.x;
      At[ac4 + 1][row] = v.y;
      At[ac4 + 2][row] = v.z;
      At[ac4 + 3][row] = v.w;
    }
    // stage W: 32 k-rows x 128 cols, 4 float4 per thread
#pragma unroll
    for (int q = 0; q < 4; ++q) {
      int row = q * 8 + wrow;
      float4 v = *(const float4*)(W + (long long)(k0 + row) * HDIM + wc4);
      *(float4*)&Ws[row][wc4] = v;
    }
    __syncthreads();

#pragma unroll 8
    for (int kk = 0; kk < TK; ++kk) {
      float4 a0 = *(const float4*)&At[kk][ty * 4];
      float4 a1 = *(const float4*)&At[kk][64 + ty * 4];
      float4 w0 = *(const float4*)&Ws[kk][tx * 4];
      float4 w1 = *(const float4*)&Ws[kk][64 + tx * 4];
      float a[8] = {a0.x, a0.y, a0.z, a0.w, a1.x, a1.y, a1.z, a1.w};
      float w[8] = {w0.x, w0.y, w0.z, w0.w, w1.x, w1.y, w1.z, w1.w};
#pragma unroll
      for (int i = 0; i < 8; ++i)
#pragma unroll
        for (int j = 0; j < 8; ++j)
          acc[i][j] += a[i] * w[j];
    }
    __syncthreads();
  }

  float bv[8];
  if (bias) {
#pragma unroll
    for (int j = 0; j < 4; ++j) {
      bv[j]     = bias[tx * 4 + j];
      bv[4 + j] = bias[64 + tx * 4 + j];
    }
  } else {
#pragma unroll
    for (int j = 0; j < 8; ++j) bv[j] = 0.f;
  }
#pragma unroll
  for (int i = 0; i < 8; ++i) {
    int row = (i < 4) ? (ty * 4 + i) : (64 + ty * 4 + i - 4);
    int gr = m0 + row;
    if (gr >= M) continue;
    float* cp = C + (long long)gr * HDIM;
    float v0[4], v1[4];
#pragma unroll
    for (int j = 0; j < 4; ++j) {
      v0[j] = acc[i][j] + bv[j];
      v1[j] = acc[i][4 + j] + bv[4 + j];
    }
    if (accumulate) {
      float4 c0 = *(const float4*)(cp + tx * 4);
      float4 c1 = *(const float4*)(cp + 64 + tx * 4);
      v0[0] += c0.x; v0[1] += c0.y; v0[2] += c0.z; v0[3] += c0.w;
      v1[0] += c1.x; v1[1] += c1.y; v1[2] += c1.z; v1[3] += c1.w;
    }
    if (post == 1) {
#pragma unroll
      for (int j = 0; j < 4; ++j) {
        v0[j] = fmaxf(v0[j], 0.f);
        v1[j] = fmaxf(v1[j], 0.f);
      }
    }
    *(float4*)(cp + tx * 4)      = make_float4(v0[0], v0[1], v0[2], v0[3]);
    *(float4*)(cp + 64 + tx * 4) = make_float4(v1[0], v1[1], v1[2], v1[3]);
  }
}

// ---------------- elementwise kernels ----------------
__global__ __launch_bounds__(256) void k_dnode(
    float* __restrict__ h, float* __restrict__ pc,
    const int* __restrict__ batch, const int* __restrict__ dom_ids,
    const float* __restrict__ dom_emb, int ntot)
{
  int idx = blockIdx.x * 256 + threadIdx.x;
  if (idx >= ntot) return;
  int n = idx >> 7, j = idx & 127;
  float d = dom_emb[dom_ids[batch[n]] * HDIM + j];
  h[idx] *= d;
  pc[idx] *= d;
}

__global__ __launch_bounds__(256) void k_combine(
    float* __restrict__ h, const float* __restrict__ pc,
    const float* __restrict__ pglin, const float* __restrict__ pa, int ntot)
{
  int idx = blockIdx.x * 256 + threadIdx.x;
  if (idx >= ntot) return;
  float pg = sigmoidf_(pglin[idx]);
  h[idx] = pg * h[idx] + (1.f - pg) * pc[idx] + pa[idx];
}

__global__ __launch_bounds__(256) void k_add(
    const float* __restrict__ a, const float* __restrict__ b,
    float* __restrict__ c, int ntot)
{
  int idx = blockIdx.x * 256 + threadIdx.x;
  if (idx >= ntot) return;
  c[idx] = a[idx] + b[idx];
}

__global__ __launch_bounds__(256) void k_out(
    const float* __restrict__ fglin, const float* __restrict__ sem,
    const float* __restrict__ stru, float* __restrict__ out, int ntot)
{
  int idx = blockIdx.x * 256 + threadIdx.x;
  if (idx >= ntot) return;
  float fg = sigmoidf_(fglin[idx]);
  out[idx] = fg * sem[idx] + (1.f - fg) * stru[idx];
}

// ---------------- graph prep kernels ----------------
__global__ __launch_bounds__(256) void k_edgecount(
    const int* __restrict__ ei, const int* __restrict__ etype,
    const int* __restrict__ epid, int* __restrict__ cntp,
    int* __restrict__ cnt8, int E)
{
  int e = blockIdx.x * 256 + threadIdx.x;
  if (e >= E) return;
  int s = ei[e];
  int d = ei[E + e];
  int et = etype[e];
  int p = epid[e];
  p = p < 0 ? 0 : (p > 15 ? 15 : p);
  atomicAdd(&cntp[s * 16 + p], 1);
  atomicAdd(&cnt8[d * 8 + et], 1);
}

__global__ __launch_bounds__(256) void k_propagg(
    const int* __restrict__ cntp, const float* __restrict__ pemb,
    float* __restrict__ pa, int ntot)
{
  int idx = blockIdx.x * 256 + threadIdx.x;
  if (idx >= ntot) return;
  int n = idx >> 7, j = idx & 127;
  int deg = 0;
  float acc = 0.f;
#pragma unroll
  for (int p = 0; p < 16; ++p) {
    int c = cntp[n * 16 + p];
    deg += c;
    acc += (float)c * pemb[p * HDIM + j];
  }
  pa[idx] = acc / (float)(deg > 1 ? deg : 1);
}

// ---- prefix scan over cnt8 (N*8 cells) -> exclusive offsets in `base` ----
__global__ __launch_bounds__(256) void s_scan1(
    const int* __restrict__ cnt, int* __restrict__ base,
    int* __restrict__ bsum, int n)
{
  __shared__ int sa[256], sb[256];
  const int tid = threadIdx.x;
  const int i0 = blockIdx.x * SCHUNK + tid * 4;
  int4 v = make_int4(0, 0, 0, 0);
  if (i0 + 4 <= n) v = *(const int4*)(cnt + i0);
  else {
    if (i0 + 0 < n) v.x = cnt[i0];
    if (i0 + 1 < n) v.y = cnt[i0 + 1];
    if (i0 + 2 < n) v.z = cnt[i0 + 2];
    if (i0 + 3 < n) v.w = cnt[i0 + 3];
  }
  int l0 = v.x, l1 = l0 + v.y, l2 = l1 + v.z, l3 = l2 + v.w;
  sa[tid] = l3;
  __syncthreads();
  int* s = sa;
  int* d = sb;
  for (int off = 1; off < 256; off <<= 1) {
    int x = s[tid];
    if (tid >= off) x += s[tid - off];
    d[tid] = x;
    __syncthreads();
    int* t = s; s = d; d = t;
  }
  int excl = s[tid] - l3;
  if (i0 + 0 < n) base[i0]     = excl;
  if (i0 + 1 < n) base[i0 + 1] = excl + l0;
  if (i0 + 2 < n) base[i0 + 2] = excl + l1;
  if (i0 + 3 < n) base[i0 + 3] = excl + l2;
  if (tid == 255) bsum[blockIdx.x] = s[255];
}

__global__ __launch_bounds__(256) void s_scan2(int* __restrict__ bsum, int n)
{
  __shared__ int sa[256], sb[256];
  const int tid = threadIdx.x;
  const int i0 = tid * 4;
  int v0 = 0, v1 = 0, v2 = 0, v3 = 0;
  if (i0 + 0 < n) v0 = bsum[i0];
  if (i0 + 1 < n) v1 = bsum[i0 + 1];
  if (i0 + 2 < n) v2 = bsum[i0 + 2];
  if (i0 + 3 < n) v3 = bsum[i0 + 3];
  int l0 = v0, l1 = l0 + v1, l2 = l1 + v2, l3 = l2 + v3;
  sa[tid] = l3;
  __syncthreads();
  int* s = sa;
  int* d = sb;
  for (int off = 1; off < 256; off <<= 1) {
    int x = s[tid];
    if (tid >= off) x += s[tid - off];
    d[tid] = x;
    __syncthreads();
    int* t = s; s = d; d = t;
  }
  int excl = s[tid] - l3;
  if (i0 + 0 < n) bsum[i0]     = excl;
  if (i0 + 1 < n) bsum[i0 + 1] = excl + l0;
  if (i0 + 2 < n) bsum[i0 + 2] = excl + l1;
  if (i0 + 3 < n) bsum[i0 + 3] = excl + l2;
}

__global__ __launch_bounds__(256) void s_scan3(
    int* __restrict__ base, const int* __restrict__ bsum, int n)
{
  int i = blockIdx.x * 256 + threadIdx.x;
  if (i < n) base[i] += bsum[i >> 10];
}

// bucket edges by (dst, relation); base[cell] becomes inclusive end afterwards
__global__ __launch_bounds__(256) void k_fill(
    const int* __restrict__ ei, const int* __restrict__ etype,
    int* __restrict__ base, int* __restrict__ srcs, int E)
{
  int e = blockIdx.x * 256 + threadIdx.x;
  if (e >= E) return;
  int s = ei[e];
  int d = ei[E + e];
  int et = etype[e];
  int pos = atomicAdd(&base[d * 8 + et], 1);
  srcs[pos] = s;
}

// agg[cell,:] = mean over bucketed src of x[src,:]  (one wave per cell; no atomics)
__global__ __launch_bounds__(256) void k_aggregate(
    const int* __restrict__ base, const int* __restrict__ cnt,
    const int* __restrict__ srcs, const float* __restrict__ x,
    float* __restrict__ agg, int ncell)
{
  int cell = (blockIdx.x * 256 + threadIdx.x) >> 6;
  int lane = threadIdx.x & 63;
  if (cell >= ncell) return;
  int c = cnt[cell];
  int end = base[cell];       // post-fill: exclusive start + c
  float ax = 0.f, ay = 0.f;
  for (int i = end - c; i < end; ++i) {
    int s = srcs[i];
    float2 v = *(const float2*)&x[(long long)s * HDIM + lane * 2];
    ax += v.x;
    ay += v.y;
  }
  float w = 1.f / (float)(c > 1 ? c : 1);
  *(float2*)&agg[(long long)cell * HDIM + lane * 2] = make_float2(ax * w, ay * w);
}

// curr_out = relu(conv + 2.0 * (x @ la) @ lb), 16 nodes per block
__global__ __launch_bounds__(256) void k_lora_relu(
    const float* __restrict__ xin, const float* __restrict__ conv,
    const float* __restrict__ la, const float* __restrict__ lb,
    float* __restrict__ outc, int NN)
{
  __shared__ float xs[16][129];
  __shared__ float las[128 * 8];
  __shared__ float lbs[8 * 128];
  __shared__ float Tsh[16][9];
  int tid = threadIdx.x;
  int n0 = blockIdx.x * 16;

  for (int i = tid; i < 1024; i += 256) {
    las[i] = la[i];
    lbs[i] = lb[i];
  }
  for (int i = tid; i < 16 * 128; i += 256) {
    int nn = i >> 7, j = i & 127;
    int g = n0 + nn;
    xs[nn][j] = (g < NN) ? xin[(long long)g * HDIM + j] : 0.f;
  }
  __syncthreads();

  if (tid < 128) {
    int nn = tid >> 3, r = tid & 7;
    float s = 0.f;
#pragma unroll 16
    for (int k = 0; k < 128; ++k) s += xs[nn][k] * las[k * 8 + r];
    Tsh[nn][r] = s;
  }
  __syncthreads();

  int nn = tid >> 4;
  int j0 = (tid & 15) * 8;
  int g = n0 + nn;
  if (g < NN) {
    const float* cv = conv + (long long)g * HDIM + j0;
    float* op = outc + (long long)g * HDIM + j0;
    float o[8];
#pragma unroll
    for (int jj = 0; jj < 8; ++jj) {
      float s = 0.f;
#pragma unroll
      for (int r = 0; r < 8; ++r) s += Tsh[nn][r] * lbs[r * HDIM + j0 + jj];
      float v = cv[jj] + 2.0f * s;   // SCALING = 16/8 = 2
      o[jj] = fmaxf(v, 0.f);
    }
    *(float4*)op = make_float4(o[0], o[1], o[2], o[3]);
    *(float4*)(op + 4) = make_float4(o[4], o[5], o[6], o[7]);
  }
}

// ---------------- host ----------------
extern "C" void kernel_launch(void* const* d_in, const int* in_sizes, int n_in,
                              void* d_out, int out_size, void* d_ws, size_t ws_size,
                              hipStream_t stream)
{
  const int N = 100000, E = 800000, TEXT = 768, H = 128, R = 8, L = 2;
  const int NTOT = N * H;
  const int NCELL = N * R;
  const int NCH = (NCELL + SCHUNK - 1) / SCHUNK;

  const float* x_text  = (const float*)d_in[0];
  const float* x_path  = (const float*)d_in[1];
  const float* text_w  = (const float*)d_in[2];
  const float* text_b  = (const float*)d_in[3];
  const float* path_w  = (const float*)d_in[4];
  const float* path_b  = (const float*)d_in[5];
  const float* dom_emb = (const float*)d_in[6];
  const float* prop_emb= (const float*)d_in[7];
  const float* pf_w    = (const float*)d_in[8];
  const float* pf_b    = (const float*)d_in[9];
  const float* pg1_w   = (const float*)d_in[10];
  const float* pg1_b   = (const float*)d_in[11];
  const float* pg2_w   = (const float*)d_in[12];
  const float* pg2_b   = (const float*)d_in[13];
  const float* sem_w   = (const float*)d_in[14];
  const float* sem_b   = (const float*)d_in[15];
  const float* str_w   = (const float*)d_in[16];
  const float* str_b   = (const float*)d_in[17];
  const float* g1_w    = (const float*)d_in[18];
  const float* g1_b    = (const float*)d_in[19];
  const float* g2_w    = (const float*)d_in[20];
  const float* g2_b    = (const float*)d_in[21];
  const float* rel_w   = (const float*)d_in[22];
  const float* root_w  = (const float*)d_in[23];
  const float* rbias   = (const float*)d_in[24];
  const float* lora_a  = (const float*)d_in[25];
  const float* lora_b  = (const float*)d_in[26];
  const int*   ei      = (const int*)d_in[27];
  const int*   etype   = (const int*)d_in[28];
  const int*   batch   = (const int*)d_in[29];
  const int*   dom_ids = (const int*)d_in[30];
  const int*   epid    = (const int*)d_in[31];
  float* out = (float*)d_out;

  const size_t NB = (size_t)NTOT * sizeof(float);   // 51.2 MB
  char* p = (char*)d_ws;
  auto alloc = [&](size_t bytes) -> void* {
    char* q = p;
    p += (bytes + 255) & ~(size_t)255;
    return (void*)q;
  };
  float* hbuf  = (float*)alloc(NB);
  float* pabuf = (float*)alloc(NB);
  float* curr  = (float*)alloc(NB);
  float* cin   = (float*)alloc(NB);
  float* conv  = (float*)alloc(NB);
  int*   cntp  = (int*)alloc((size_t)N * 16 * 4);   // cntp+cnt8 contiguous (one memset)
  int*   cnt8  = (int*)alloc((size_t)N * 8 * 4);
  int*   base  = (int*)alloc((size_t)NCELL * 4);
  int*   srcs  = (int*)alloc((size_t)E * 4);
  int*   bsum  = (int*)alloc((size_t)1024 * 4);
  float* agg   = (float*)alloc((size_t)NCELL * H * sizeof(float));  // 409.6 MB

  const int GM = (N + TM - 1) / TM;
  const int EWG = (NTOT + 255) / 256;

  auto gemm = [&](const float* A, const float* W, const float* b, float* C,
                  int K, int accv, int post) {
    gemm128<<<dim3(GM), dim3(256), 0, stream>>>(A, W, b, C, N, K, accv, post);
  };

  // --- graph prep: counts, (dst,rel)-CSR, property aggregation ---
  hipMemsetAsync(cntp, 0, (size_t)N * 24 * 4, stream);
  k_edgecount<<<(E + 255) / 256, 256, 0, stream>>>(ei, etype, epid, cntp, cnt8, E);
  k_propagg<<<EWG, 256, 0, stream>>>(cntp, prop_emb, pabuf, NTOT);
  s_scan1<<<NCH, 256, 0, stream>>>(cnt8, base, bsum, NCELL);
  s_scan2<<<1, 256, 0, stream>>>(bsum, NCH);
  s_scan3<<<(NCELL + 255) / 256, 256, 0, stream>>>(base, bsum, NCELL);
  k_fill<<<(E + 255) / 256, 256, 0, stream>>>(ei, etype, base, srcs, E);

  // --- front-end: projections, domain modulation, path gate ---
  gemm(x_text, text_w, text_b, hbuf, TEXT, 0, 0);
  gemm(x_path, path_w, path_b, curr, TEXT, 0, 0);
  k_dnode<<<EWG, 256, 0, stream>>>(hbuf, curr, batch, dom_ids, dom_emb, NTOT);
  gemm(curr, pf_w, pf_b, cin, H, 0, 0);                  // path_ctx
  gemm(hbuf, pg1_w, pg1_b, conv, H, 0, 0);               // h part
  gemm(cin, pg1_w + H * H, nullptr, conv, H, 1, 1);      // + pc part, relu
  gemm(conv, pg2_w, pg2_b, curr, H, 0, 0);               // pgate linear (curr free)
  k_combine<<<EWG, 256, 0, stream>>>(hbuf, cin, curr, pabuf, NTOT);

  // --- RGCN layers: aggregate-first, single K=1024 relation GEMM ---
  for (int l = 0; l < L; ++l) {
    const float* src = (l == 0) ? hbuf : curr;
    k_add<<<EWG, 256, 0, stream>>>(src, pabuf, cin, NTOT);          // curr_in
    k_aggregate<<<NCELL / 4, 256, 0, stream>>>(base, cnt8, srcs, cin, agg, NCELL);
    gemm(agg, rel_w + (size_t)l * R * H * H, rbias + (size_t)l * H,
         conv, R * H, 0, 0);                                        // sum_r agg_r @ W_r + bias
    gemm(cin, root_w + (size_t)l * H * H, nullptr, conv, H, 1, 0);  // + root
    k_lora_relu<<<(N + 15) / 16, 256, 0, stream>>>(
        cin, conv, lora_a + (size_t)l * H * 8, lora_b + (size_t)l * 8 * H,
        curr, N);
  }

  // --- final gated fusion ---
  gemm(hbuf, sem_w, sem_b, conv, H, 0, 0);               // sem
  gemm(curr, str_w, str_b, cin, H, 0, 0);                // stru
  gemm(conv, g1_w, g1_b, pabuf, H, 0, 0);
  gemm(cin, g1_w + H * H, nullptr, pabuf, H, 1, 1);      // relu
  gemm(pabuf, g2_w, g2_b, hbuf, H, 0, 0);                // fg linear
  k_out<<<EWG, 256, 0, stream>>>(hbuf, conv, cin, out, NTOT);
}